// Round 1
// baseline (186.842 us; speedup 1.0000x reference)
//
#include <hip/hip_runtime.h>

// 8 lanes cooperate on one batch element; hidden dim 10 padded to 16 (2 units/lane).
#define LPE 8
#define CH 16   // t-prefetch chunk length (steps)

#if __has_builtin(__builtin_amdgcn_exp2f)
  #define EXP2F(x) __builtin_amdgcn_exp2f(x)
#else
  #define EXP2F(x) exp2f(x)
#endif
#if __has_builtin(__builtin_amdgcn_rcpf)
  #define RCPF(x) __builtin_amdgcn_rcpf(x)
#else
  #define RCPF(x) (1.0f/(x))
#endif

__device__ __forceinline__ float fast_tanh(float x) {
    // tanh(x) = 1 - 2/(e^{2x}+1);  e^{2x} = exp2(x * 2*log2(e))
    float z = EXP2F(x * 2.88539008177792681472f);
    return fmaf(-2.0f, RCPF(z + 1.0f), 1.0f);
}

template<int CTRL>
__device__ __forceinline__ float dpp_add(float x) {
    int y = __builtin_amdgcn_update_dpp(0, __float_as_int(x), CTRL, 0xF, 0xF, true);
    return x + __int_as_float(y);
}

// Butterfly sum across the 8-lane group (lanes 8k..8k+7). All lanes get the total.
__device__ __forceinline__ float reduce8(float x) {
    x = dpp_add<0xB1>(x);   // quad_perm(1,0,3,2) : xor 1
    x = dpp_add<0x4E>(x);   // quad_perm(2,3,0,1) : xor 2
    x = dpp_add<0x141>(x);  // row_half_mirror    : pair across quads within 8
    return x;
}

__global__ __launch_bounds__(256, 1) void ode_scan(
    const float* __restrict__ t,
    const float* __restrict__ Vs,
    const float* __restrict__ Tm,
    const float* __restrict__ C0,
    const float* __restrict__ R0,
    const float* __restrict__ W1,   // (5,10) row-major
    const float* __restrict__ b1,   // (10)
    const float* __restrict__ W2,   // (10,5) row-major
    const float* __restrict__ b2,   // (5)
    float* __restrict__ out,        // (B, N+1, 2)
    int B, int N)
{
    int tid = blockIdx.x * blockDim.x + threadIdx.x;
    int e = tid >> 3;      // element
    int u = tid & 7;       // lane within group
    if (e >= B) return;

    float Vv = Vs[e], Tv = Tm[e];

    // Per-lane weights for hidden units j = 2u, 2u+1 (j>=10 are zero dummies).
    float w0[2], w3[2], w4[2], cc[2], v3[2], v4[2];
#pragma unroll
    for (int m = 0; m < 2; ++m) {
        int j = 2*u + m;
        if (j < 10) {
            w0[m] = W1[j];          // W1[0][j] : coef of t
            cc[m] = fmaf(Vv, W1[10+j], fmaf(Tv, W1[20+j], b1[j]));  // folded const
            w3[m] = W1[30+j];       // coef of Cap
            w4[m] = W1[40+j];       // coef of Res
            v3[m] = W2[5*j+3];      // -> output col 3 (Cap)
            v4[m] = W2[5*j+4];      // -> output col 4 (Res)
        } else {
            w0[m]=0.f; w3[m]=0.f; w4[m]=0.f; cc[m]=0.f; v3[m]=0.f; v4[m]=0.f;
        }
    }
    float bo3 = b2[3], bo4 = b2[4];

    float Cap = C0[e], Res = R0[e];
    const float* trow = t + (size_t)e * (N + 1);
    float tc = trow[0];
    float* orow = out + (size_t)e * (size_t)(N + 1) * 2;
    *(float2*)orow = make_float2(Cap, Res);   // y0 row

#define STEP(TN, DST) do {                                                   \
        float tn_ = (TN);                                                    \
        float h_  = tn_ - tc;                                                \
        float a0_ = fmaf(Res, w4[0], fmaf(Cap, w3[0], fmaf(tc, w0[0], cc[0])));\
        float a1_ = fmaf(Res, w4[1], fmaf(Cap, w3[1], fmaf(tc, w0[1], cc[1])));\
        float t0_ = fast_tanh(a0_);                                          \
        float t1_ = fast_tanh(a1_);                                          \
        float p3_ = fmaf(t1_, v3[1], t0_ * v3[0]);                           \
        float p4_ = fmaf(t1_, v4[1], t0_ * v4[0]);                           \
        p3_ = reduce8(p3_);                                                  \
        p4_ = reduce8(p4_);                                                  \
        Cap = fmaf(h_, p3_ + bo3, Cap);                                      \
        Res = fmaf(h_, p4_ + bo4, Res);                                      \
        tc  = tn_;                                                           \
        (DST) = make_float2(Cap, Res);                                       \
    } while (0)

    int i = 1;  // next step index (t index / out row)
    if (N >= 2*CH) {
        float bufA[CH], bufB[CH];
#pragma unroll
        for (int m = 0; m < CH; ++m) bufA[m] = trow[1 + m];
#pragma unroll
        for (int m = 0; m < CH; ++m) bufB[m] = trow[1 + CH + m];

        int npair = N / (2*CH);
        float2* op = (float2*)orow + 1;
        for (int p = 0; p < npair; ++p) {
            int c = 2*p;
            // ---- process chunk c (bufA), then refill bufA with chunk c+2 ----
#pragma unroll
            for (int m = 0; m < CH; ++m) STEP(bufA[m], op[m]);
            {
                int base = 1 + (c + 2)*CH;
#pragma unroll
                for (int m = 0; m < CH; ++m) {
                    int idx = base + m; idx = idx > N ? N : idx;
                    bufA[m] = trow[idx];
                }
            }
            op += CH;
            // ---- process chunk c+1 (bufB), then refill bufB with chunk c+3 ----
#pragma unroll
            for (int m = 0; m < CH; ++m) STEP(bufB[m], op[m]);
            {
                int base = 1 + (c + 3)*CH;
#pragma unroll
                for (int m = 0; m < CH; ++m) {
                    int idx = base + m; idx = idx > N ? N : idx;
                    bufB[m] = trow[idx];
                }
            }
            op += CH;
        }
        i = 2*CH*npair + 1;
    }
    // scalar tail (not hit for N=2048)
    for (; i <= N; ++i) {
        float tn = trow[i];
        STEP(tn, *(float2*)(orow + 2*(size_t)i));
    }
#undef STEP
}

extern "C" void kernel_launch(void* const* d_in, const int* in_sizes, int n_in,
                              void* d_out, int out_size, void* d_ws, size_t ws_size,
                              hipStream_t stream) {
    const float* t  = (const float*)d_in[0];
    const float* Vs = (const float*)d_in[1];
    const float* Tm = (const float*)d_in[2];
    const float* C0 = (const float*)d_in[3];
    const float* R0 = (const float*)d_in[4];
    const float* W1 = (const float*)d_in[5];
    const float* b1 = (const float*)d_in[6];
    const float* W2 = (const float*)d_in[7];
    const float* b2 = (const float*)d_in[8];
    float* out = (float*)d_out;

    int B = in_sizes[1];                 // V_sto has B elements
    int N = in_sizes[0] / B - 1;         // t has B*(N+1)

    int threads = B * LPE;
    dim3 block(256);
    dim3 grid((threads + 255) / 256);
    hipLaunchKernelGGL(ode_scan, grid, block, 0, stream,
                       t, Vs, Tm, C0, R0, W1, b1, W2, b2, out, B, N);
}

// Round 2
// 179.437 us; speedup vs baseline: 1.0413x; 1.0413x over previous
//
#include <hip/hip_runtime.h>

// 8 lanes per batch element; 2 hidden units per lane (10 real + dummies).
#define LPE 8
#define CH 16   // steps per software-pipeline chunk

#if __has_builtin(__builtin_amdgcn_exp2f)
  #define EXP2F(x) __builtin_amdgcn_exp2f(x)
#else
  #define EXP2F(x) exp2f(x)
#endif
#if __has_builtin(__builtin_amdgcn_rcpf)
  #define RCPF(x) __builtin_amdgcn_rcpf(x)
#else
  #define RCPF(x) (1.0f/(x))
#endif

template<int CTRL>
__device__ __forceinline__ float dpp_add(float x) {
    int y = __builtin_amdgcn_update_dpp(0, __float_as_int(x), CTRL, 0xF, 0xF, true);
    return x + __int_as_float(y);
}
// Butterfly sum across each aligned 8-lane group; all 8 lanes get the total.
__device__ __forceinline__ float reduce8(float x) {
    x = dpp_add<0xB1>(x);   // xor 1 (quad_perm 1,0,3,2)
    x = dpp_add<0x4E>(x);   // xor 2 (quad_perm 2,3,0,1)
    x = dpp_add<0x141>(x);  // row_half_mirror == xor 7 after previous stages
    return x;
}

__global__ __launch_bounds__(256, 1) void ode_scan(
    const float* __restrict__ t,
    const float* __restrict__ Vs,
    const float* __restrict__ Tm,
    const float* __restrict__ C0,
    const float* __restrict__ R0,
    const float* __restrict__ W1,   // (5,10)
    const float* __restrict__ b1,   // (10)
    const float* __restrict__ W2,   // (10,5)
    const float* __restrict__ b2,   // (5)
    float* __restrict__ out,        // (B, N+1, 2)
    int B, int N)
{
    int tid = blockIdx.x * blockDim.x + threadIdx.x;
    int e = tid >> 3;
    int u = tid & 7;
    if (e >= B) return;

    const float S = 2.88539008177792681472f;   // 2*log2(e)
    float Vv = Vs[e], Tv = Tm[e];

    // Per-lane folded weights for hidden units j0=2u, j1=2u+1.
    float w0s0,w0s1,w3s0,w3s1,w4s0,w4s1,cc0,cc1,v30,v31,v40,v41;
    {
        int j0 = 2*u, j1 = 2*u + 1;
        if (j0 < 10) {
            w0s0 = S*W1[j0]; w3s0 = S*W1[30+j0]; w4s0 = S*W1[40+j0];
            cc0  = S*fmaf(Vv, W1[10+j0], fmaf(Tv, W1[20+j0], b1[j0]));
            v30  = -2.0f*W2[5*j0+3]; v40 = -2.0f*W2[5*j0+4];
        } else { w0s0=0.f; w3s0=0.f; w4s0=0.f; cc0=-60.f; v30=0.f; v40=0.f; }
        if (j1 < 10) {
            w0s1 = S*W1[j1]; w3s1 = S*W1[30+j1]; w4s1 = S*W1[40+j1];
            cc1  = S*fmaf(Vv, W1[10+j1], fmaf(Tv, W1[20+j1], b1[j1]));
            v31  = -2.0f*W2[5*j1+3]; v41 = -2.0f*W2[5*j1+4];
        } else { w0s1=0.f; w3s1=0.f; w4s1=0.f; cc1=-60.f; v31=0.f; v41=0.f; }
        if (j0 == 10) {
            // dummy "constant" unit: a = -60 -> z=2^-60 -> 1+z==1.0f -> r==1.0 exactly.
            float c3 = b2[3], c4 = b2[4];
            for (int j = 0; j < 10; ++j) { c3 += W2[5*j+3]; c4 += W2[5*j+4]; }
            v30 = c3; v40 = c4;
        }
    }

    float Cap = C0[e], Res = R0[e];
    const float* trow = t + (size_t)e * (N + 1);
    float* orow = out + (size_t)e * (size_t)(N + 1) * 2;
    *(float2*)orow = make_float2(Cap, Res);

    // One scan step. Serial chain: Cap/Res -> 2 FMA -> exp2 -> add -> rcp -> mul/fma -> reduce -> fma.
#define STEP(HH, TP0, TP1, DST) do {                                        \
        float a0_ = fmaf(Res, w4s0, fmaf(Cap, w3s0, (TP0)));                \
        float a1_ = fmaf(Res, w4s1, fmaf(Cap, w3s1, (TP1)));                \
        float r0_ = RCPF(EXP2F(a0_) + 1.0f);                                \
        float r1_ = RCPF(EXP2F(a1_) + 1.0f);                                \
        float p3_ = fmaf(r1_, v31, r0_ * v30);                              \
        float p4_ = fmaf(r1_, v41, r0_ * v40);                              \
        p3_ = reduce8(p3_);                                                 \
        p4_ = reduce8(p4_);                                                 \
        Cap = fmaf((HH), p3_, Cap);                                         \
        Res = fmaf((HH), p4_, Res);                                         \
        (DST) = make_float2(Cap, Res);                                      \
    } while (0)

    // Issue CH clamped loads of t[BASE..BASE+CH-1] into RAW.
#define LOADCH(RAW, BASE) do {                                              \
        _Pragma("unroll")                                                   \
        for (int m_ = 0; m_ < CH; ++m_) {                                   \
            int idx_ = (BASE) + m_; idx_ = idx_ > N ? N : idx_;             \
            (RAW)[m_] = trow[idx_];                                         \
        }                                                                   \
    } while (0)

    // t-only derived quantities for a chunk: h[m] = t_i - t_{i-1}, tp[m] = fma(t_{i-1}, w0, cc).
#define DERIVE(H, T0, T1, RAW, CARRY) do {                                  \
        float prev_ = (CARRY);                                              \
        _Pragma("unroll")                                                   \
        for (int m_ = 0; m_ < CH; ++m_) {                                   \
            (H)[m_]  = (RAW)[m_] - prev_;                                   \
            (T0)[m_] = fmaf(prev_, w0s0, cc0);                              \
            (T1)[m_] = fmaf(prev_, w0s1, cc1);                              \
            prev_ = (RAW)[m_];                                              \
        }                                                                   \
    } while (0)

#define PROC(H, T0, T1, OP) do {                                            \
        _Pragma("unroll")                                                   \
        for (int m_ = 0; m_ < CH; ++m_) STEP((H)[m_], (T0)[m_], (T1)[m_], (OP)[m_]); \
    } while (0)

    int i = 1;
    if (N >= 2*CH) {
        float rawA[CH], rawB[CH];
        float hA[CH], tA0[CH], tA1[CH];
        float hB[CH], tB0[CH], tB1[CH];

        float tfirst = trow[0];
        LOADCH(rawA, 1);            // chunk 0
        LOADCH(rawB, 1 + CH);       // chunk 1
        DERIVE(hA, tA0, tA1, rawA, tfirst);
        float carryB = rawA[CH-1];
        DERIVE(hB, tB0, tB1, rawB, carryB);
        LOADCH(rawA, 1 + 2*CH);     // chunk 2 in flight

        int npair = N / (2*CH);
        float2* op = (float2*)orow + 1;
        for (int p = 0; p < npair; ++p) {
            int c = 2*p;
            // process chunk c
            PROC(hA, tA0, tA1, op);
            op += CH;
            // derive chunk c+2 from rawA (carry = last t of chunk c+1, still in rawB)
            DERIVE(hA, tA0, tA1, rawA, rawB[CH-1]);
            LOADCH(rawB, 1 + (c + 3)*CH);      // chunk c+3 in flight
            // process chunk c+1
            PROC(hB, tB0, tB1, op);
            op += CH;
            // derive chunk c+3 from rawB (carry = last t of chunk c+2 = rawA[15])
            DERIVE(hB, tB0, tB1, rawB, rawA[CH-1]);
            LOADCH(rawA, 1 + (c + 4)*CH);      // chunk c+4 in flight
        }
        i = 2*CH*npair + 1;
    }
    // generic scalar tail (not hit for N=2048)
    for (; i <= N; ++i) {
        float tcv = trow[i-1];
        float h_  = trow[i] - tcv;
        float tp0 = fmaf(tcv, w0s0, cc0);
        float tp1 = fmaf(tcv, w0s1, cc1);
        STEP(h_, tp0, tp1, *(float2*)(orow + 2*(size_t)i));
    }
#undef STEP
#undef LOADCH
#undef DERIVE
#undef PROC
}

extern "C" void kernel_launch(void* const* d_in, const int* in_sizes, int n_in,
                              void* d_out, int out_size, void* d_ws, size_t ws_size,
                              hipStream_t stream) {
    const float* t  = (const float*)d_in[0];
    const float* Vs = (const float*)d_in[1];
    const float* Tm = (const float*)d_in[2];
    const float* C0 = (const float*)d_in[3];
    const float* R0 = (const float*)d_in[4];
    const float* W1 = (const float*)d_in[5];
    const float* b1 = (const float*)d_in[6];
    const float* W2 = (const float*)d_in[7];
    const float* b2 = (const float*)d_in[8];
    float* out = (float*)d_out;

    int B = in_sizes[1];
    int N = in_sizes[0] / B - 1;

    int threads = B * LPE;
    dim3 block(256);
    dim3 grid((threads + 255) / 256);
    hipLaunchKernelGGL(ode_scan, grid, block, 0, stream,
                       t, Vs, Tm, C0, R0, W1, b1, W2, b2, out, B, N);
}